// Round 1
// baseline (751.002 us; speedup 1.0000x reference)
//
#include <hip/hip_runtime.h>

// SingleLSTM: B=32768, T=28, INPUT=28, HIDDEN=128, LABELS=10, fp32.
// R14: occupancy 2x. R13 ran 1 block/CU (86KB LDS), 8 waves = 2/SIMD;
// counters showed VALU+trans ~55%, MFMA ~31%, ~45% stall -> latency-bound
// at 2 waves/SIMD. Now: 64 rows/block, 512 blocks, 512 threads; LDS
// h_s 34816B + xs 8192B + wx_s 32768B = 75776B -> exactly 2 blocks/CU
// (151552 <= 160K; 3 blocks LDS-impossible), 16 waves/CU = 4/SIMD.
// Register budget 128 (pool 512/SIMD at 4 waves): W_x fragments moved
// to LDS (-16 regs, 1 conflict-free b128 read per gate per tile), acc
// ping-pong dropped (-16 regs; inter-wave TLP + two independent block
// barriers replace intra-wave pipelining), creg 32->16 with row split.
// Kept from R4-R13: fp16 datapath, wave owns 16 hidden cols x 4 gates,
// per-lane c/h update, early global x loads / late LDS writes, W/bias
// pre-scaled {-L2E, 2L2E, -L2E, -L2E}, c in 2*L2E units, one barrier
// per step via h double-buffer.

typedef _Float16 f16x8 __attribute__((ext_vector_type(8)));
typedef float f32x4 __attribute__((ext_vector_type(4)));

#define HSTRIDE 136    // f16 elems; 272B row = 17*16B (b128-aligned rows)
#define L2E 1.44269504f

__global__ __launch_bounds__(512, 4)
void lstm_r14(const float* __restrict__ x,      // [B][28][28]
              const float* __restrict__ W,      // [156][512]
              const float* __restrict__ b,      // [512]
              const float* __restrict__ Wfc,    // [128][10]
              const float* __restrict__ bfc,    // [10]
              float* __restrict__ out)          // [B][10]
{
    __shared__ __align__(16) _Float16 h_s[2][64 * HSTRIDE];   // 34816 B
    __shared__ __align__(16) _Float16 xs[2][4 * 512];         //  8192 B
    __shared__ __align__(16) _Float16 wx_s[8][4][64][8];      // 32768 B
    // total 75776 B

    const int tid  = threadIdx.x;
    const int wave = tid >> 6;
    const int lane = tid & 63;
    const int m16  = lane & 15;
    const int quad = lane >> 4;
    const int rbase = blockIdx.x * 64;
    const int hc = wave * 16 + m16;     // this lane's hidden column

    // ---- zero h buf0 and xs (k>=28 slots must stay 0 forever) ----
    for (int i = tid; i < 64 * HSTRIDE; i += 512) h_s[0][i] = (_Float16)0.0f;
    for (int i = tid; i < 2 * 4 * 512; i += 512) ((_Float16*)xs)[i] = (_Float16)0.0f;

    // ---- W fragments (fp16, pre-scaled); Wx goes to LDS, Wh stays in regs
    f16x8 Wh[4][4];
    float bias[4];
    #pragma unroll
    for (int g = 0; g < 4; g++) {
        const int col = g * 128 + hc;
        const float sc = (g == 1) ? 2.0f * L2E : -L2E;
        bias[g] = sc * (b[col] + (g == 2 ? 1.0f : 0.0f));   // FORGET_BIAS folded
        f16x8 w8;
        #pragma unroll
        for (int j = 0; j < 8; j++) {
            int kk = quad * 8 + j;
            w8[j] = (kk < 28) ? (_Float16)(sc * W[kk * 512 + col]) : (_Float16)0.0f;
        }
        *(f16x8*)&wx_s[wave][g][lane][0] = w8;
        #pragma unroll
        for (int ks = 0; ks < 4; ks++) {
            f16x8 h8;
            #pragma unroll
            for (int j = 0; j < 8; j++)
                h8[j] = (_Float16)(sc * W[(28 + ks * 32 + quad * 8 + j) * 512 + col]);
            Wh[ks][g] = h8;
        }
    }

    // barrier: zero-init + wx_s writes must complete before t=0 staging/reads
    __syncthreads();

    // ---- x staging: 64 rows x 28 k = 1792 = 3.5 slots x 512 threads ----
    // slot e: idx = e*512+tid; LDS offset into flattened xs[buf] (chunk =
    // srow>>4, A-frag order inside chunk); global offset relative to x+t*28.
    int lsoff[4], goff[4];
    #pragma unroll
    for (int e = 0; e < 4; e++) {
        const int idx = e * 512 + tid;
        const int srow = idx / 28, sk = idx % 28;
        lsoff[e] = (srow >> 4) * 512 + (sk >> 3) * 128 + (srow & 15) * 8 + (sk & 7);
        goff[e]  = (rbase + srow) * 784 + sk;   // < 25.7M, fits int
    }
    const bool e3ok = tid < 256;   // slot 3 is half-valid (1792 = 3.5*512)

    // stage x for t=0
    #pragma unroll
    for (int e = 0; e < 4; e++)
        if (e < 3 || e3ok) xs[0][lsoff[e]] = (_Float16)x[goff[e]];
    __syncthreads();

    float creg[16];
    #pragma unroll
    for (int i = 0; i < 16; i++) creg[i] = 0.0f;

    const int foff = quad * 128 + m16 * 8;          // A-frag offset inside a chunk
    const _Float16* wxp = &wx_s[wave][0][lane][0];  // + g*512 per gate

    int buf = 0;
    for (int t = 0; t < 28; t++) {
        const int nb = buf ^ 1;

        // ---- EARLY: issue global loads for t+1 (wait lands at step end) ----
        float xv[4];
        if (t < 27) {
            const float* xt = x + (t + 1) * 28;
            #pragma unroll
            for (int e = 0; e < 4; e++)
                if (e < 3 || e3ok) xv[e] = xt[goff[e]];
        }

        // ---- 4 tiles: MFMA chain then activation; overlap comes from
        // 4 waves/SIMD + two phase-independent blocks per CU ----
        #pragma unroll
        for (int mt = 0; mt < 4; mt++) {
            f32x4 acc[4];
            f16x8 ax = *(const f16x8*)(&xs[buf][mt * 512 + foff]);
            #pragma unroll
            for (int g = 0; g < 4; g++) {
                f16x8 wx = *(const f16x8*)(wxp + g * 512);
                acc[g] = (f32x4){bias[g], bias[g], bias[g], bias[g]};
                acc[g] = __builtin_amdgcn_mfma_f32_16x16x32_f16(ax, wx, acc[g], 0, 0, 0);
            }
            #pragma unroll
            for (int ks = 0; ks < 4; ks++) {
                f16x8 ah = *(const f16x8*)(&h_s[buf][(mt * 16 + m16) * HSTRIDE + ks * 32 + quad * 8]);
                #pragma unroll
                for (int g = 0; g < 4; g++)
                    acc[g] = __builtin_amdgcn_mfma_f32_16x16x32_f16(ah, Wh[ks][g], acc[g], 0, 0, 0);
            }

            // activation for tile mt; per-lane c/h update
            #pragma unroll
            for (int r = 0; r < 4; r++) {
                float ei  = __builtin_amdgcn_exp2f(acc[0][r]);   // e^-i
                float e2j = __builtin_amdgcn_exp2f(acc[1][r]);   // e^2j
                float ef  = __builtin_amdgcn_exp2f(acc[2][r]);   // e^-(f+1)
                float eo  = __builtin_amdgcn_exp2f(acc[3][r]);   // e^-o
                float A   = 1.0f + ei;
                float Bv  = e2j + 1.0f;
                float C   = 1.0f + ef;
                float AB  = A * Bv;
                float rP  = __builtin_amdgcn_rcpf(AB * C);
                float num = __builtin_fmaf(e2j, 2.0f * L2E, -2.0f * L2E);
                float cn  = __builtin_fmaf(creg[mt * 4 + r], AB * rP, num * (C * rP));
                creg[mt * 4 + r] = cn;
                float e2c = __builtin_amdgcn_exp2f(cn);          // e^2c
                float rQ  = __builtin_amdgcn_rcpf((e2c + 1.0f) * (1.0f + eo));
                float hv  = (e2c - 1.0f) * rQ;
                h_s[nb][(mt * 16 + quad * 4 + r) * HSTRIDE + hc] = (_Float16)hv;
            }
        }

        // ---- LATE: stage x(t+1) to LDS (vmcnt satisfied long ago) ----
        if (t < 27) {
            #pragma unroll
            for (int e = 0; e < 4; e++)
                if (e < 3 || e3ok) xs[nb][lsoff[e]] = (_Float16)xv[e];
        }
        __syncthreads();
        buf = nb;
    }

    // ---- FC epilogue: logits = h @ Wfc + bfc (640 outputs) ----
    for (int i = tid; i < 640; i += 512) {
        const int row = i / 10, lab = i % 10;
        float acc = bfc[lab];
        #pragma unroll 8
        for (int k = 0; k < 128; k++)
            acc += (float)h_s[buf][row * HSTRIDE + k] * Wfc[k * 10 + lab];
        out[(size_t)(rbase + row) * 10 + lab] = acc;
    }
}

extern "C" void kernel_launch(void* const* d_in, const int* in_sizes, int n_in,
                              void* d_out, int out_size, void* d_ws, size_t ws_size,
                              hipStream_t stream) {
    const float* x   = (const float*)d_in[0];
    const float* W   = (const float*)d_in[1];
    const float* b   = (const float*)d_in[2];
    const float* Wfc = (const float*)d_in[3];
    const float* bfc = (const float*)d_in[4];
    float* out = (float*)d_out;

    const int B = in_sizes[0] / (28 * 28);   // 32768
    const int blocks = B / 64;               // 512 = two per CU
    lstm_r14<<<blocks, 512, 0, stream>>>(x, W, b, Wfc, bfc, out);
}

// Round 3
// 607.029 us; speedup vs baseline: 1.2372x; 1.2372x over previous
//
#include <hip/hip_runtime.h>

// SingleLSTM: B=32768, T=28, INPUT=28, HIDDEN=128, LABELS=10, fp32.
// R16: R14's 2-blocks/CU occupancy plan, spill fixed by register-demand
// reduction + AGPR placement pinning, MFMA back to builtins (R15's raw
// asm MFMA lacked hazard s_nops -> NaN; builtins get them from the
// compiler).
//   - Wh fragments pinned to AGPRs via empty asm("":"+a") (64 AGPR).
//     Builtin MFMA reads SrcB from AGPR natively; no per-use copies.
//   - bias folded into the GEMM: x slots k=28,29 hold constant 1.0,
//     Wx LDS rows 28/29 hold hi/lo two-f16 split of pre-scaled bias
//     (FORGET folded). acc inits to literal 0. (-4 arch regs)
//   - linear staging: LDS slot = e*512+tid (affine); global addr
//     decoded from slot: goff[e] = goff0 + e*12544 -> 1 reg not 8.
//     validity (sk<28) is one reusable predicate; LDS image identical
//     to the old permuted staging, coalescing identical.
// Arch demand ~40 <= 48 (accum_offset 80), total ~120 <= 128.
// 64 rows/block, 512 blocks, 512 threads; LDS h_s 34816 + xs 8192 +
// wx_s 32768 = 75776 B -> exactly 2 blocks/CU, 16 waves/CU = 4/SIMD.
// Kept from R4-R13: fp16 datapath, wave owns 16 hidden cols x 4 gates,
// per-lane c/h update, early global x loads / late LDS writes, W/bias
// pre-scaled {-L2E, 2L2E, -L2E, -L2E}, c in 2*L2E units, one barrier
// per step via h double-buffer, HSTRIDE=136 (17*16B) conflict-free rows.

typedef _Float16 f16x8 __attribute__((ext_vector_type(8)));
typedef float f32x4 __attribute__((ext_vector_type(4)));

#define HSTRIDE 136    // f16 elems; 272B row = 17*16B (b128-aligned rows)
#define L2E 1.44269504f

__global__ __launch_bounds__(512, 4)
void lstm_r16(const float* __restrict__ x,      // [B][28][28]
              const float* __restrict__ W,      // [156][512]
              const float* __restrict__ b,      // [512]
              const float* __restrict__ Wfc,    // [128][10]
              const float* __restrict__ bfc,    // [10]
              float* __restrict__ out)          // [B][10]
{
    __shared__ __align__(16) _Float16 h_s[2][64 * HSTRIDE];   // 34816 B
    __shared__ __align__(16) _Float16 xs[2][4 * 512];         //  8192 B
    __shared__ __align__(16) _Float16 wx_s[8][4][64][8];      // 32768 B
    // total 75776 B -> 2 blocks/CU

    const int tid  = threadIdx.x;
    const int wave = tid >> 6;
    const int lane = tid & 63;
    const int m16  = lane & 15;
    const int quad = lane >> 4;
    const int rbase = blockIdx.x * 64;
    const int hc = wave * 16 + m16;     // this lane's hidden column

    // ---- zero h buf0; xs: k=28,29 slots = 1.0 (bias lane), rest 0 ----
    for (int i = tid; i < 64 * HSTRIDE; i += 512) h_s[0][i] = (_Float16)0.0f;
    for (int i = tid; i < 2 * 4 * 512; i += 512) {
        const int q = i & 511;          // position within 512-elem chunk
        const bool bslot = ((q >> 7) == 3) && (((q & 7) == 4) || ((q & 7) == 5));
        ((_Float16*)xs)[i] = bslot ? (_Float16)1.0f : (_Float16)0.0f;
    }

    // ---- W fragments (fp16, pre-scaled); Wx+bias to LDS, Wh to AGPRs ----
    f16x8 Wh[4][4];
    #pragma unroll
    for (int g = 0; g < 4; g++) {
        const int col = g * 128 + hc;
        const float sc = (g == 1) ? 2.0f * L2E : -L2E;
        f16x8 w8;
        #pragma unroll
        for (int j = 0; j < 8; j++) {
            const int kk = quad * 8 + j;
            w8[j] = (kk < 28) ? (_Float16)(sc * W[kk * 512 + col]) : (_Float16)0.0f;
        }
        if (quad == 3) {
            // kk==28/29: two-f16 hi/lo split of pre-scaled bias (FORGET folded)
            const float bv = sc * (b[col] + (g == 2 ? 1.0f : 0.0f));
            const _Float16 hi = (_Float16)bv;
            w8[4] = hi;
            w8[5] = (_Float16)(bv - (float)hi);
        }
        *(f16x8*)&wx_s[wave][g][lane][0] = w8;
        #pragma unroll
        for (int ks = 0; ks < 4; ks++) {
            f16x8 h8;
            #pragma unroll
            for (int j = 0; j < 8; j++)
                h8[j] = (_Float16)(sc * W[(28 + ks * 32 + quad * 8 + j) * 512 + col]);
            Wh[ks][g] = h8;
        }
    }
    // pin the 64-reg Wh array into AGPRs (semantic no-op; removes the
    // allocator's R14 choice of keeping Wh in arch VGPRs and spilling)
    #pragma unroll
    for (int ks = 0; ks < 4; ks++)
        #pragma unroll
        for (int g = 0; g < 4; g++)
            asm("" : "+a"(Wh[ks][g]));

    // barrier: zero/bias-init + wx_s writes must complete before t=0 staging
    __syncthreads();

    // ---- x staging, linear form: LDS slot = e*512 + tid ----
    // decode slot -> (srow = e*16 + row16, sk); valid iff sk < 28.
    // global offset = (rbase+srow)*784 + sk + t*28 = goff0 + e*12544 + t*28.
    const int row16 = (tid >> 3) & 15;
    const int sk    = ((tid >> 7) & 3) * 8 + (tid & 7);
    const bool valid = (sk < 28);
    const int goff0 = (rbase + row16) * 784 + sk;   // < 25.7M, fits int

    // stage x for t=0
    #pragma unroll
    for (int e = 0; e < 4; e++)
        if (valid) xs[0][e * 512 + tid] = (_Float16)x[goff0 + e * 12544];
    __syncthreads();

    float creg[16];
    #pragma unroll
    for (int i = 0; i < 16; i++) creg[i] = 0.0f;

    const int foff = quad * 128 + m16 * 8;          // A-frag offset in a chunk
    const _Float16* wxp = &wx_s[wave][0][lane][0];  // + g*512 per gate

    int buf = 0;
    for (int t = 0; t < 28; t++) {
        const int nb = buf ^ 1;

        // ---- EARLY: issue global loads for t+1 (wait lands at step end) ----
        float xv[4];
        if (t < 27 && valid) {
            const float* xt = x + (t + 1) * 28;
            #pragma unroll
            for (int e = 0; e < 4; e++) xv[e] = xt[goff0 + e * 12544];
        }

        // ---- 4 tiles: MFMA chain (builtin; acc->AGPR naturally) + act ----
        #pragma unroll
        for (int mt = 0; mt < 4; mt++) {
            f32x4 acc[4];
            f16x8 ax = *(const f16x8*)(&xs[buf][mt * 512 + foff]);
            #pragma unroll
            for (int g = 0; g < 4; g++) {
                f16x8 wx = *(const f16x8*)(wxp + g * 512);
                acc[g] = (f32x4){0.0f, 0.0f, 0.0f, 0.0f};
                acc[g] = __builtin_amdgcn_mfma_f32_16x16x32_f16(ax, wx, acc[g], 0, 0, 0);
            }
            #pragma unroll
            for (int ks = 0; ks < 4; ks++) {
                f16x8 ah = *(const f16x8*)(&h_s[buf][(mt * 16 + m16) * HSTRIDE + ks * 32 + quad * 8]);
                #pragma unroll
                for (int g = 0; g < 4; g++)
                    acc[g] = __builtin_amdgcn_mfma_f32_16x16x32_f16(ah, Wh[ks][g], acc[g], 0, 0, 0);
            }

            // activation for tile mt; per-lane c/h update
            #pragma unroll
            for (int r = 0; r < 4; r++) {
                float ei  = __builtin_amdgcn_exp2f(acc[0][r]);   // e^-i
                float e2j = __builtin_amdgcn_exp2f(acc[1][r]);   // e^2j
                float ef  = __builtin_amdgcn_exp2f(acc[2][r]);   // e^-(f+1)
                float eo  = __builtin_amdgcn_exp2f(acc[3][r]);   // e^-o
                float A   = 1.0f + ei;
                float Bv  = e2j + 1.0f;
                float C   = 1.0f + ef;
                float AB  = A * Bv;
                float rP  = __builtin_amdgcn_rcpf(AB * C);
                float num = __builtin_fmaf(e2j, 2.0f * L2E, -2.0f * L2E);
                float cn  = __builtin_fmaf(creg[mt * 4 + r], AB * rP, num * (C * rP));
                creg[mt * 4 + r] = cn;
                float e2c = __builtin_amdgcn_exp2f(cn);          // e^2c
                float rQ  = __builtin_amdgcn_rcpf((e2c + 1.0f) * (1.0f + eo));
                float hv  = (e2c - 1.0f) * rQ;
                h_s[nb][(mt * 16 + quad * 4 + r) * HSTRIDE + hc] = (_Float16)hv;
            }
        }

        // ---- LATE: stage x(t+1) to LDS (vmcnt satisfied long ago) ----
        if (t < 27 && valid) {
            #pragma unroll
            for (int e = 0; e < 4; e++)
                xs[nb][e * 512 + tid] = (_Float16)xv[e];
        }
        __syncthreads();
        buf = nb;
    }

    // ---- FC epilogue: logits = h @ Wfc + bfc (640 outputs) ----
    for (int i = tid; i < 640; i += 512) {
        const int row = i / 10, lab = i % 10;
        float acc = bfc[lab];
        #pragma unroll 8
        for (int k = 0; k < 128; k++)
            acc += (float)h_s[buf][row * HSTRIDE + k] * Wfc[k * 10 + lab];
        out[(size_t)(rbase + row) * 10 + lab] = acc;
    }
}

extern "C" void kernel_launch(void* const* d_in, const int* in_sizes, int n_in,
                              void* d_out, int out_size, void* d_ws, size_t ws_size,
                              hipStream_t stream) {
    const float* x   = (const float*)d_in[0];
    const float* W   = (const float*)d_in[1];
    const float* b   = (const float*)d_in[2];
    const float* Wfc = (const float*)d_in[3];
    const float* bfc = (const float*)d_in[4];
    float* out = (float*)d_out;

    const int B = in_sizes[0] / (28 * 28);   // 32768
    const int blocks = B / 64;               // 512 = two per CU
    lstm_r16<<<blocks, 512, 0, stream>>>(x, W, b, Wfc, bfc, out);
}

// Round 4
// 314.040 us; speedup vs baseline: 2.3914x; 1.9330x over previous
//
#include <hip/hip_runtime.h>

// SingleLSTM: B=32768, T=28, INPUT=28, HIDDEN=128, LABELS=10, fp32.
// R17: back to R13's verified geometry (128 rows/block, 256 blocks,
// 86KB LDS -> 1 block/CU, 8 waves, 256-reg budget; R14/R15/R16's
// 2-block plan is register-infeasible, proven by 3 rounds of spill).
// New vs R13:
//  - sched_group_barrier interleave in the tile loop: R13's counters
//    (Mfma 31 + VALU 55 + ~14 dead = 100%) show the pipes run
//    SEQUENTIALLY: the ping-pong's 20-MFMA burst stalls the wave at
//    in-order issue (~390cy @ 19.4cy/MFMA) before it reaches the act
//    VALU. Emit {1 MFMA, 5 VALU} x20 per tile (+5 ds_read front, 4
//    ds_write back) so one wave feeds both pipes.
//  - bias folded into GEMM (verified R16): x k=28,29 slots = 1.0, Wx
//    frag carries hi/lo two-f16 bias split on quad==3; acc init = ZERO
//    const via MFMA D!=C -> kills 128 bias-splat v_movs per step.
//  - linear staging (verified R16): LDS slot = e*512+tid, global addr
//    goff0 + e*12544 + t*28; k>=28 slots written once at init.
// Kept: fp16 datapath, wave owns 16 hidden cols x 4 gates, per-lane
// c/h update, early global x loads / late LDS writes, W/bias pre-scaled
// {-L2E, 2L2E, -L2E, -L2E}, c in 2*L2E units, one barrier per step via
// h double-buffer, HSTRIDE=136 conflict-free rows, acc[2][4] ping-pong
// with static cur/nxt indices.

typedef _Float16 f16x8 __attribute__((ext_vector_type(8)));
typedef float f32x4 __attribute__((ext_vector_type(4)));

#define HSTRIDE 136    // f16 elems; 272B row = 17*16B (b128-aligned rows)
#define L2E 1.44269504f

__global__ __launch_bounds__(512, 2)
void lstm_r17(const float* __restrict__ x,      // [B][28][28]
              const float* __restrict__ W,      // [156][512]
              const float* __restrict__ b,      // [512]
              const float* __restrict__ Wfc,    // [128][10]
              const float* __restrict__ bfc,    // [10]
              float* __restrict__ out)          // [B][10]
{
    __shared__ __align__(16) _Float16 h_s[2][128 * HSTRIDE];  // 69632 B
    __shared__ __align__(16) _Float16 xs[2][8 * 512];         // 16384 B
    // total 86016 B: >80 KB -> exactly one block resident per CU

    const int tid  = threadIdx.x;
    const int wave = tid >> 6;
    const int lane = tid & 63;
    const int m16  = lane & 15;
    const int quad = lane >> 4;
    const int rbase = blockIdx.x * 128;
    const int hc = wave * 16 + m16;     // this lane's hidden column

    // ---- zero h buf0; xs: k=28,29 slots = 1.0 (bias lanes), rest 0 ----
    for (int i = tid; i < 128 * HSTRIDE; i += 512) h_s[0][i] = (_Float16)0.0f;
    for (int i = tid; i < 2 * 8 * 512; i += 512) {
        const int q = i & 511;          // position within 512-elem chunk
        const bool bslot = ((q >> 7) == 3) && (((q & 7) == 4) || ((q & 7) == 5));
        ((_Float16*)xs)[i] = bslot ? (_Float16)1.0f : (_Float16)0.0f;
    }

    // ---- W fragments (fp16, pre-scaled), all in registers ----
    f16x8 Wx[4];
    f16x8 Wh[4][4];
    #pragma unroll
    for (int g = 0; g < 4; g++) {
        const int col = g * 128 + hc;
        const float sc = (g == 1) ? 2.0f * L2E : -L2E;
        f16x8 w8;
        #pragma unroll
        for (int j = 0; j < 8; j++) {
            const int kk = quad * 8 + j;
            w8[j] = (kk < 28) ? (_Float16)(sc * W[kk * 512 + col]) : (_Float16)0.0f;
        }
        if (quad == 3) {
            // kk==28/29: two-f16 hi/lo split of pre-scaled bias (FORGET folded)
            const float bv = sc * (b[col] + (g == 2 ? 1.0f : 0.0f));
            const _Float16 hi = (_Float16)bv;
            w8[4] = hi;
            w8[5] = (_Float16)(bv - (float)hi);
        }
        Wx[g] = w8;
        #pragma unroll
        for (int ks = 0; ks < 4; ks++) {
            f16x8 h8;
            #pragma unroll
            for (int j = 0; j < 8; j++)
                h8[j] = (_Float16)(sc * W[(28 + ks * 32 + quad * 8 + j) * 512 + col]);
            Wh[ks][g] = h8;
        }
    }

    // barrier: zero/bias init must complete before t=0 staging (R6 race)
    __syncthreads();

    // ---- x staging, linear form: LDS slot = e*512 + tid ----
    // decode tid -> (row16, sk); valid iff sk < 28; slots sk>=28 were
    // initialized (0 or bias 1.0) and are never rewritten.
    // global offset = (rbase + e*16 + row16)*784 + sk + t*28.
    const int row16 = (tid >> 3) & 15;
    const int sk    = ((tid >> 7) & 3) * 8 + (tid & 7);
    const bool valid = (sk < 28);
    const int goff0 = (rbase + row16) * 784 + sk;   // < 25.7M, fits int

    // stage x for t=0
    #pragma unroll
    for (int e = 0; e < 8; e++)
        if (valid) xs[0][e * 512 + tid] = (_Float16)x[goff0 + e * 12544];
    __syncthreads();

    float creg[32];
    #pragma unroll
    for (int i = 0; i < 32; i++) creg[i] = 0.0f;

    const int foff = quad * 128 + m16 * 8;   // A-frag offset inside a chunk
    const f32x4 ZERO = (f32x4){0.0f, 0.0f, 0.0f, 0.0f};

    int buf = 0;
    for (int t = 0; t < 28; t++) {
        const int nb = buf ^ 1;

        // ---- EARLY: issue global loads for t+1 (wait lands at step end) ----
        float xv[8];
        if (t < 27 && valid) {
            const float* xt = x + (t + 1) * 28;
            #pragma unroll
            for (int e = 0; e < 8; e++) xv[e] = xt[goff0 + e * 12544];
        }

        f32x4 acc[2][4];

        // prologue: tile 0 MFMA chain -> acc[0] (bias comes via the fold)
        {
            f16x8 ax = *(const f16x8*)(&xs[buf][foff]);
            #pragma unroll
            for (int g = 0; g < 4; g++)
                acc[0][g] = __builtin_amdgcn_mfma_f32_16x16x32_f16(ax, Wx[g], ZERO, 0, 0, 0);
            #pragma unroll
            for (int ks = 0; ks < 4; ks++) {
                f16x8 ah = *(const f16x8*)(&h_s[buf][m16 * HSTRIDE + ks * 32 + quad * 8]);
                #pragma unroll
                for (int g = 0; g < 4; g++)
                    acc[0][g] = __builtin_amdgcn_mfma_f32_16x16x32_f16(ah, Wh[ks][g], acc[0][g], 0, 0, 0);
            }
        }

        #pragma unroll
        for (int mt = 0; mt < 8; mt++) {
            const int cur = mt & 1, nxt = cur ^ 1;

            // issue tile mt+1's MFMA chain before act(mt)
            if (mt < 7) {
                f16x8 axn = *(const f16x8*)(&xs[buf][(mt + 1) * 512 + foff]);
                #pragma unroll
                for (int g = 0; g < 4; g++)
                    acc[nxt][g] = __builtin_amdgcn_mfma_f32_16x16x32_f16(axn, Wx[g], ZERO, 0, 0, 0);
                #pragma unroll
                for (int ks = 0; ks < 4; ks++) {
                    f16x8 ahn = *(const f16x8*)(&h_s[buf][((mt + 1) * 16 + m16) * HSTRIDE + ks * 32 + quad * 8]);
                    #pragma unroll
                    for (int g = 0; g < 4; g++)
                        acc[nxt][g] = __builtin_amdgcn_mfma_f32_16x16x32_f16(ahn, Wh[ks][g], acc[nxt][g], 0, 0, 0);
                }
            }

            // activation for tile mt (reads acc[cur]); per-lane c/h update
            #pragma unroll
            for (int r = 0; r < 4; r++) {
                float ei  = __builtin_amdgcn_exp2f(acc[cur][0][r]);   // e^-i
                float e2j = __builtin_amdgcn_exp2f(acc[cur][1][r]);   // e^2j
                float ef  = __builtin_amdgcn_exp2f(acc[cur][2][r]);   // e^-(f+1)
                float eo  = __builtin_amdgcn_exp2f(acc[cur][3][r]);   // e^-o
                float A   = 1.0f + ei;
                float Bv  = e2j + 1.0f;
                float C   = 1.0f + ef;
                float AB  = A * Bv;
                float rP  = __builtin_amdgcn_rcpf(AB * C);
                float num = __builtin_fmaf(e2j, 2.0f * L2E, -2.0f * L2E);
                float cn  = __builtin_fmaf(creg[mt * 4 + r], AB * rP, num * (C * rP));
                creg[mt * 4 + r] = cn;
                float e2c = __builtin_amdgcn_exp2f(cn);               // e^2c
                float rQ  = __builtin_amdgcn_rcpf((e2c + 1.0f) * (1.0f + eo));
                float hv  = (e2c - 1.0f) * rQ;
                h_s[nb][(mt * 16 + quad * 4 + r) * HSTRIDE + hc] = (_Float16)hv;
            }

            // ---- scheduling directive: break the MFMA burst ----
            // per tile: 5 ds_read_b128 up front, then {1 MFMA, 5 VALU}x20
            // (20 MFMA : ~100 VALU+trans available), 4 ds_write_b16 last.
            __builtin_amdgcn_sched_group_barrier(0x100, 5, 0);   // DS_READ
            #pragma unroll
            for (int rep = 0; rep < 20; rep++) {
                __builtin_amdgcn_sched_group_barrier(0x008, 1, 0); // MFMA
                __builtin_amdgcn_sched_group_barrier(0x002, 5, 0); // VALU
            }
            __builtin_amdgcn_sched_group_barrier(0x200, 4, 0);   // DS_WRITE
        }

        // ---- LATE: stage x(t+1) to LDS (vmcnt satisfied long ago) ----
        if (t < 27 && valid) {
            #pragma unroll
            for (int e = 0; e < 8; e++)
                xs[nb][e * 512 + tid] = (_Float16)xv[e];
        }
        __syncthreads();
        buf = nb;
    }

    // ---- FC epilogue: logits = h @ Wfc + bfc (1280 outputs) ----
    for (int i = tid; i < 1280; i += 512) {
        const int row = i / 10, lab = i % 10;
        float acc = bfc[lab];
        #pragma unroll 8
        for (int k = 0; k < 128; k++)
            acc += (float)h_s[buf][row * HSTRIDE + k] * Wfc[k * 10 + lab];
        out[(size_t)(rbase + row) * 10 + lab] = acc;
    }
}

extern "C" void kernel_launch(void* const* d_in, const int* in_sizes, int n_in,
                              void* d_out, int out_size, void* d_ws, size_t ws_size,
                              hipStream_t stream) {
    const float* x   = (const float*)d_in[0];
    const float* W   = (const float*)d_in[1];
    const float* b   = (const float*)d_in[2];
    const float* Wfc = (const float*)d_in[3];
    const float* bfc = (const float*)d_in[4];
    float* out = (float*)d_out;

    const int B = in_sizes[0] / (28 * 28);   // 32768
    const int blocks = B / 128;              // 256 = one per CU
    lstm_r17<<<blocks, 512, 0, stream>>>(x, W, b, Wfc, bfc, out);
}

// Round 5
// 309.200 us; speedup vs baseline: 2.4289x; 1.0157x over previous
//
#include <hip/hip_runtime.h>

// SingleLSTM: B=32768, T=28, INPUT=28, HIDDEN=128, LABELS=10, fp32.
// R18: R17 minus sched_group_barrier (net-negative: my VALU-mask groups
// missed TRANS-class exp2/rcp -> unsatisfiable pipeline; 214->225us),
// plus engineered wave antiphase via asymmetric s_setprio.
// Ledger (R13/R17 counters): per SIMD per step, MFMA-pipe work ~6.2k cy
// + VALU work ~9.6k cy ~= measured 19.3k cy -> pipes run SERIALLY. The
// 2 waves/SIMD exit each step barrier together and execute an identical
// [20-MFMA burst][act] x8 rhythm -> both contend for the matrix pipe,
// then both for VALU (lockstep). Fix: waves with (wave&4) raise prio
// around their MFMA chains only. At barrier exit the prio-1 wave
// monopolizes the matrix pipe and bursts; its partner stalls in-order,
// then bursts while the first does act at prio0 -> self-sustaining
// antiphase, matrix pipe fed while VALU chews act (m114 overlap).
// Kept (verified R16/R17): bias folded into GEMM (x k=28,29 slots=1.0,
// Wx frag carries hi/lo two-f16 bias split on quad==3, acc init=ZERO
// via MFMA D!=C), linear staging (LDS slot = e*512+tid, global =
// goff0 + e*12544 + t*28). Geometry: 128 rows/block, 256 blocks, 512
// thr, 86KB LDS -> 1 block/CU, 8 waves (2/SIMD), 256-reg budget.
// fp16 datapath; wave owns 16 hidden cols x 4 gates; per-lane c/h
// update; early global x loads / late LDS writes; W/bias pre-scaled
// {-L2E, 2L2E, -L2E, -L2E}; c in 2*L2E units; one barrier per step via
// h double-buffer; HSTRIDE=136 conflict-free rows; acc[2][4] ping-pong.

typedef _Float16 f16x8 __attribute__((ext_vector_type(8)));
typedef float f32x4 __attribute__((ext_vector_type(4)));

#define HSTRIDE 136    // f16 elems; 272B row = 17*16B (b128-aligned rows)
#define L2E 1.44269504f

__global__ __launch_bounds__(512, 2)
void lstm_r18(const float* __restrict__ x,      // [B][28][28]
              const float* __restrict__ W,      // [156][512]
              const float* __restrict__ b,      // [512]
              const float* __restrict__ Wfc,    // [128][10]
              const float* __restrict__ bfc,    // [10]
              float* __restrict__ out)          // [B][10]
{
    __shared__ __align__(16) _Float16 h_s[2][128 * HSTRIDE];  // 69632 B
    __shared__ __align__(16) _Float16 xs[2][8 * 512];         // 16384 B
    // total 86016 B: >80 KB -> exactly one block resident per CU

    const int tid  = threadIdx.x;
    const int wave = tid >> 6;
    const int lane = tid & 63;
    const int m16  = lane & 15;
    const int quad = lane >> 4;
    const int rbase = blockIdx.x * 128;
    const int hc = wave * 16 + m16;     // this lane's hidden column
    // waves {4..7} share SIMDs with waves {0..3} (round-robin dispatch):
    // they get priority during MFMA chains -> antiphase vs partner wave
    const bool hipri = (wave & 4) != 0;

    // ---- zero h buf0; xs: k=28,29 slots = 1.0 (bias lanes), rest 0 ----
    for (int i = tid; i < 128 * HSTRIDE; i += 512) h_s[0][i] = (_Float16)0.0f;
    for (int i = tid; i < 2 * 8 * 512; i += 512) {
        const int q = i & 511;          // position within 512-elem chunk
        const bool bslot = ((q >> 7) == 3) && (((q & 7) == 4) || ((q & 7) == 5));
        ((_Float16*)xs)[i] = bslot ? (_Float16)1.0f : (_Float16)0.0f;
    }

    // ---- W fragments (fp16, pre-scaled), all in registers ----
    f16x8 Wx[4];
    f16x8 Wh[4][4];
    #pragma unroll
    for (int g = 0; g < 4; g++) {
        const int col = g * 128 + hc;
        const float sc = (g == 1) ? 2.0f * L2E : -L2E;
        f16x8 w8;
        #pragma unroll
        for (int j = 0; j < 8; j++) {
            const int kk = quad * 8 + j;
            w8[j] = (kk < 28) ? (_Float16)(sc * W[kk * 512 + col]) : (_Float16)0.0f;
        }
        if (quad == 3) {
            // kk==28/29: two-f16 hi/lo split of pre-scaled bias (FORGET folded)
            const float bv = sc * (b[col] + (g == 2 ? 1.0f : 0.0f));
            const _Float16 hi = (_Float16)bv;
            w8[4] = hi;
            w8[5] = (_Float16)(bv - (float)hi);
        }
        Wx[g] = w8;
        #pragma unroll
        for (int ks = 0; ks < 4; ks++) {
            f16x8 h8;
            #pragma unroll
            for (int j = 0; j < 8; j++)
                h8[j] = (_Float16)(sc * W[(28 + ks * 32 + quad * 8 + j) * 512 + col]);
            Wh[ks][g] = h8;
        }
    }

    // barrier: zero/bias init must complete before t=0 staging (R6 race)
    __syncthreads();

    // ---- x staging, linear form: LDS slot = e*512 + tid ----
    const int row16 = (tid >> 3) & 15;
    const int sk    = ((tid >> 7) & 3) * 8 + (tid & 7);
    const bool valid = (sk < 28);
    const int goff0 = (rbase + row16) * 784 + sk;   // < 25.7M, fits int

    // stage x for t=0
    #pragma unroll
    for (int e = 0; e < 8; e++)
        if (valid) xs[0][e * 512 + tid] = (_Float16)x[goff0 + e * 12544];
    __syncthreads();

    float creg[32];
    #pragma unroll
    for (int i = 0; i < 32; i++) creg[i] = 0.0f;

    const int foff = quad * 128 + m16 * 8;   // A-frag offset inside a chunk
    const f32x4 ZERO = (f32x4){0.0f, 0.0f, 0.0f, 0.0f};

    int buf = 0;
    for (int t = 0; t < 28; t++) {
        const int nb = buf ^ 1;

        // ---- EARLY: issue global loads for t+1 (wait lands at step end) ----
        float xv[8];
        if (t < 27 && valid) {
            const float* xt = x + (t + 1) * 28;
            #pragma unroll
            for (int e = 0; e < 8; e++) xv[e] = xt[goff0 + e * 12544];
        }

        f32x4 acc[2][4];

        // prologue: tile 0 MFMA chain -> acc[0] (bias comes via the fold)
        {
            if (hipri) __builtin_amdgcn_s_setprio(1);
            f16x8 ax = *(const f16x8*)(&xs[buf][foff]);
            #pragma unroll
            for (int g = 0; g < 4; g++)
                acc[0][g] = __builtin_amdgcn_mfma_f32_16x16x32_f16(ax, Wx[g], ZERO, 0, 0, 0);
            #pragma unroll
            for (int ks = 0; ks < 4; ks++) {
                f16x8 ah = *(const f16x8*)(&h_s[buf][m16 * HSTRIDE + ks * 32 + quad * 8]);
                #pragma unroll
                for (int g = 0; g < 4; g++)
                    acc[0][g] = __builtin_amdgcn_mfma_f32_16x16x32_f16(ah, Wh[ks][g], acc[0][g], 0, 0, 0);
            }
            if (hipri) __builtin_amdgcn_s_setprio(0);
        }

        #pragma unroll
        for (int mt = 0; mt < 8; mt++) {
            const int cur = mt & 1, nxt = cur ^ 1;

            // issue tile mt+1's MFMA chain before act(mt)
            if (mt < 7) {
                if (hipri) __builtin_amdgcn_s_setprio(1);
                f16x8 axn = *(const f16x8*)(&xs[buf][(mt + 1) * 512 + foff]);
                #pragma unroll
                for (int g = 0; g < 4; g++)
                    acc[nxt][g] = __builtin_amdgcn_mfma_f32_16x16x32_f16(axn, Wx[g], ZERO, 0, 0, 0);
                #pragma unroll
                for (int ks = 0; ks < 4; ks++) {
                    f16x8 ahn = *(const f16x8*)(&h_s[buf][((mt + 1) * 16 + m16) * HSTRIDE + ks * 32 + quad * 8]);
                    #pragma unroll
                    for (int g = 0; g < 4; g++)
                        acc[nxt][g] = __builtin_amdgcn_mfma_f32_16x16x32_f16(ahn, Wh[ks][g], acc[nxt][g], 0, 0, 0);
                }
                if (hipri) __builtin_amdgcn_s_setprio(0);
            }

            // activation for tile mt (reads acc[cur]); per-lane c/h update
            #pragma unroll
            for (int r = 0; r < 4; r++) {
                float ei  = __builtin_amdgcn_exp2f(acc[cur][0][r]);   // e^-i
                float e2j = __builtin_amdgcn_exp2f(acc[cur][1][r]);   // e^2j
                float ef  = __builtin_amdgcn_exp2f(acc[cur][2][r]);   // e^-(f+1)
                float eo  = __builtin_amdgcn_exp2f(acc[cur][3][r]);   // e^-o
                float A   = 1.0f + ei;
                float Bv  = e2j + 1.0f;
                float C   = 1.0f + ef;
                float AB  = A * Bv;
                float rP  = __builtin_amdgcn_rcpf(AB * C);
                float num = __builtin_fmaf(e2j, 2.0f * L2E, -2.0f * L2E);
                float cn  = __builtin_fmaf(creg[mt * 4 + r], AB * rP, num * (C * rP));
                creg[mt * 4 + r] = cn;
                float e2c = __builtin_amdgcn_exp2f(cn);               // e^2c
                float rQ  = __builtin_amdgcn_rcpf((e2c + 1.0f) * (1.0f + eo));
                float hv  = (e2c - 1.0f) * rQ;
                h_s[nb][(mt * 16 + quad * 4 + r) * HSTRIDE + hc] = (_Float16)hv;
            }
        }

        // ---- LATE: stage x(t+1) to LDS (vmcnt satisfied long ago) ----
        if (t < 27 && valid) {
            #pragma unroll
            for (int e = 0; e < 8; e++)
                xs[nb][e * 512 + tid] = (_Float16)xv[e];
        }
        __syncthreads();
        buf = nb;
    }

    // ---- FC epilogue: logits = h @ Wfc + bfc (1280 outputs) ----
    for (int i = tid; i < 1280; i += 512) {
        const int row = i / 10, lab = i % 10;
        float acc = bfc[lab];
        #pragma unroll 8
        for (int k = 0; k < 128; k++)
            acc += (float)h_s[buf][row * HSTRIDE + k] * Wfc[k * 10 + lab];
        out[(size_t)(rbase + row) * 10 + lab] = acc;
    }
}

extern "C" void kernel_launch(void* const* d_in, const int* in_sizes, int n_in,
                              void* d_out, int out_size, void* d_ws, size_t ws_size,
                              hipStream_t stream) {
    const float* x   = (const float*)d_in[0];
    const float* W   = (const float*)d_in[1];
    const float* b   = (const float*)d_in[2];
    const float* Wfc = (const float*)d_in[3];
    const float* bfc = (const float*)d_in[4];
    float* out = (float*)d_out;

    const int B = in_sizes[0] / (28 * 28);   // 32768
    const int blocks = B / 128;              // 256 = one per CU
    lstm_r18<<<blocks, 512, 0, stream>>>(x, W, b, Wfc, bfc, out);
}

// Round 6
// 299.687 us; speedup vs baseline: 2.5060x; 1.0317x over previous
//
#include <hip/hip_runtime.h>

// SingleLSTM: B=32768, T=28, INPUT=28, HIDDEN=128, LABELS=10, fp32.
// R19: 2-stage fragment software pipeline. Counter re-read (R13-R18):
// VALUBusy on CDNA includes MFMA issue -> true ledger per SIMD-step is
// MFMA 6.2k cy + VALU-only ~4.4k cy, ~45% STALL. The stall is lgkmcnt:
// R13/R17/R18 issue tile mt+1's 5 ds_read_b128 right before the 20
// MFMAs that consume them -> ~120cy LDS-latency wait heads every tile
// chain, both waves phase-locked -> SIMD idles. Fix: iteration mt
// issues ds_reads for tile mt+1 (off buffer), MFMAs tile mt from frags
// loaded one full iteration (~500cy MFMA) ago, acts tile mt-1. MFMA
// chain and act are independent (different acc buffers) so the
// post-RA scheduler can interleave them freely. Scheduling hacks
// removed (SGB R17 and setprio R18 both regressed).
// Kept (verified): bias folded into GEMM (x k=28,29 slots=1.0, Wx frag
// carries hi/lo two-f16 bias split on quad==3, acc init=ZERO via MFMA
// D!=C), linear staging (LDS slot = e*512+tid, global = goff0 +
// e*12544 + t*28), geometry 128 rows/block, 256 blocks, 512 thr, 86KB
// LDS -> 1 block/CU, 8 waves (2/SIMD), 256-reg budget, fp16 datapath,
// wave owns 16 hidden cols x 4 gates, per-lane c/h update, early
// global x loads / late LDS writes, W/bias pre-scaled {-L2E, 2L2E,
// -L2E, -L2E}, c in 2*L2E units, one barrier/step via h double-buffer,
// HSTRIDE=136 conflict-free rows.

typedef _Float16 f16x8 __attribute__((ext_vector_type(8)));
typedef float f32x4 __attribute__((ext_vector_type(4)));

#define HSTRIDE 136    // f16 elems; 272B row = 17*16B (b128-aligned rows)
#define L2E 1.44269504f

__global__ __launch_bounds__(512, 2)
void lstm_r19(const float* __restrict__ x,      // [B][28][28]
              const float* __restrict__ W,      // [156][512]
              const float* __restrict__ b,      // [512]
              const float* __restrict__ Wfc,    // [128][10]
              const float* __restrict__ bfc,    // [10]
              float* __restrict__ out)          // [B][10]
{
    __shared__ __align__(16) _Float16 h_s[2][128 * HSTRIDE];  // 69632 B
    __shared__ __align__(16) _Float16 xs[2][8 * 512];         // 16384 B
    // total 86016 B: >80 KB -> exactly one block resident per CU

    const int tid  = threadIdx.x;
    const int wave = tid >> 6;
    const int lane = tid & 63;
    const int m16  = lane & 15;
    const int quad = lane >> 4;
    const int rbase = blockIdx.x * 128;
    const int hc = wave * 16 + m16;     // this lane's hidden column

    // ---- zero h buf0; xs: k=28,29 slots = 1.0 (bias lanes), rest 0 ----
    for (int i = tid; i < 128 * HSTRIDE; i += 512) h_s[0][i] = (_Float16)0.0f;
    for (int i = tid; i < 2 * 8 * 512; i += 512) {
        const int q = i & 511;          // position within 512-elem chunk
        const bool bslot = ((q >> 7) == 3) && (((q & 7) == 4) || ((q & 7) == 5));
        ((_Float16*)xs)[i] = bslot ? (_Float16)1.0f : (_Float16)0.0f;
    }

    // ---- W fragments (fp16, pre-scaled), all in registers ----
    f16x8 Wx[4];
    f16x8 Wh[4][4];
    #pragma unroll
    for (int g = 0; g < 4; g++) {
        const int col = g * 128 + hc;
        const float sc = (g == 1) ? 2.0f * L2E : -L2E;
        f16x8 w8;
        #pragma unroll
        for (int j = 0; j < 8; j++) {
            const int kk = quad * 8 + j;
            w8[j] = (kk < 28) ? (_Float16)(sc * W[kk * 512 + col]) : (_Float16)0.0f;
        }
        if (quad == 3) {
            // kk==28/29: two-f16 hi/lo split of pre-scaled bias (FORGET folded)
            const float bv = sc * (b[col] + (g == 2 ? 1.0f : 0.0f));
            const _Float16 hi = (_Float16)bv;
            w8[4] = hi;
            w8[5] = (_Float16)(bv - (float)hi);
        }
        Wx[g] = w8;
        #pragma unroll
        for (int ks = 0; ks < 4; ks++) {
            f16x8 h8;
            #pragma unroll
            for (int j = 0; j < 8; j++)
                h8[j] = (_Float16)(sc * W[(28 + ks * 32 + quad * 8 + j) * 512 + col]);
            Wh[ks][g] = h8;
        }
    }

    // barrier: zero/bias init must complete before t=0 staging (R6 race)
    __syncthreads();

    // ---- x staging, linear form: LDS slot = e*512 + tid ----
    const int row16 = (tid >> 3) & 15;
    const int sk    = ((tid >> 7) & 3) * 8 + (tid & 7);
    const bool valid = (sk < 28);
    const int goff0 = (rbase + row16) * 784 + sk;   // < 25.7M, fits int

    // stage x for t=0
    #pragma unroll
    for (int e = 0; e < 8; e++)
        if (valid) xs[0][e * 512 + tid] = (_Float16)x[goff0 + e * 12544];
    __syncthreads();

    float creg[32];
    #pragma unroll
    for (int i = 0; i < 32; i++) creg[i] = 0.0f;

    const int foff = quad * 128 + m16 * 8;   // A-frag offset inside a chunk
    const f32x4 ZERO = (f32x4){0.0f, 0.0f, 0.0f, 0.0f};

    int buf = 0;
    for (int t = 0; t < 28; t++) {
        const int nb = buf ^ 1;

        // ---- EARLY: issue global loads for t+1 (wait lands at step end) ----
        float xv[8];
        if (t < 27 && valid) {
            const float* xt = x + (t + 1) * 28;
            #pragma unroll
            for (int e = 0; e < 8; e++) xv[e] = xt[goff0 + e * 12544];
        }

        // ---- 2-stage pipeline over 8 tiles:
        //   iter mt: ds_read frag(mt+1) | MFMA tile mt | act tile mt-1
        f16x8 Fax[2];
        f16x8 Fah[2][4];
        f32x4 acc[2][4];

        // prologue: load fragments for tile 0
        Fax[0] = *(const f16x8*)(&xs[buf][foff]);
        #pragma unroll
        for (int ks = 0; ks < 4; ks++)
            Fah[0][ks] = *(const f16x8*)(&h_s[buf][m16 * HSTRIDE + ks * 32 + quad * 8]);

        #pragma unroll
        for (int mt = 0; mt < 8; mt++) {
            const int cur = mt & 1, nxt = cur ^ 1;

            // issue ds_reads for tile mt+1 (consumed next iteration)
            if (mt < 7) {
                Fax[nxt] = *(const f16x8*)(&xs[buf][(mt + 1) * 512 + foff]);
                #pragma unroll
                for (int ks = 0; ks < 4; ks++)
                    Fah[nxt][ks] = *(const f16x8*)(&h_s[buf][((mt + 1) * 16 + m16) * HSTRIDE + ks * 32 + quad * 8]);
            }

            // MFMA chain for tile mt (fragments loaded last iteration)
            #pragma unroll
            for (int g = 0; g < 4; g++)
                acc[cur][g] = __builtin_amdgcn_mfma_f32_16x16x32_f16(Fax[cur], Wx[g], ZERO, 0, 0, 0);
            #pragma unroll
            for (int ks = 0; ks < 4; ks++)
                #pragma unroll
                for (int g = 0; g < 4; g++)
                    acc[cur][g] = __builtin_amdgcn_mfma_f32_16x16x32_f16(Fah[cur][ks], Wh[ks][g], acc[cur][g], 0, 0, 0);

            // activation for tile mt-1 (reads acc[nxt]); independent of the
            // MFMA chain above -> scheduler may interleave freely
            if (mt > 0) {
                const int pt = mt - 1;
                #pragma unroll
                for (int r = 0; r < 4; r++) {
                    float ei  = __builtin_amdgcn_exp2f(acc[nxt][0][r]);   // e^-i
                    float e2j = __builtin_amdgcn_exp2f(acc[nxt][1][r]);   // e^2j
                    float ef  = __builtin_amdgcn_exp2f(acc[nxt][2][r]);   // e^-(f+1)
                    float eo  = __builtin_amdgcn_exp2f(acc[nxt][3][r]);   // e^-o
                    float A   = 1.0f + ei;
                    float Bv  = e2j + 1.0f;
                    float C   = 1.0f + ef;
                    float AB  = A * Bv;
                    float rP  = __builtin_amdgcn_rcpf(AB * C);
                    float num = __builtin_fmaf(e2j, 2.0f * L2E, -2.0f * L2E);
                    float cn  = __builtin_fmaf(creg[pt * 4 + r], AB * rP, num * (C * rP));
                    creg[pt * 4 + r] = cn;
                    float e2c = __builtin_amdgcn_exp2f(cn);               // e^2c
                    float rQ  = __builtin_amdgcn_rcpf((e2c + 1.0f) * (1.0f + eo));
                    float hv  = (e2c - 1.0f) * rQ;
                    h_s[nb][(pt * 16 + quad * 4 + r) * HSTRIDE + hc] = (_Float16)hv;
                }
            }
        }

        // epilogue: activation for tile 7 (acc[1])
        {
            #pragma unroll
            for (int r = 0; r < 4; r++) {
                float ei  = __builtin_amdgcn_exp2f(acc[1][0][r]);
                float e2j = __builtin_amdgcn_exp2f(acc[1][1][r]);
                float ef  = __builtin_amdgcn_exp2f(acc[1][2][r]);
                float eo  = __builtin_amdgcn_exp2f(acc[1][3][r]);
                float A   = 1.0f + ei;
                float Bv  = e2j + 1.0f;
                float C   = 1.0f + ef;
                float AB  = A * Bv;
                float rP  = __builtin_amdgcn_rcpf(AB * C);
                float num = __builtin_fmaf(e2j, 2.0f * L2E, -2.0f * L2E);
                float cn  = __builtin_fmaf(creg[28 + r], AB * rP, num * (C * rP));
                creg[28 + r] = cn;
                float e2c = __builtin_amdgcn_exp2f(cn);
                float rQ  = __builtin_amdgcn_rcpf((e2c + 1.0f) * (1.0f + eo));
                float hv  = (e2c - 1.0f) * rQ;
                h_s[nb][(112 + quad * 4 + r) * HSTRIDE + hc] = (_Float16)hv;
            }
        }

        // ---- LATE: stage x(t+1) to LDS (vmcnt satisfied long ago) ----
        if (t < 27 && valid) {
            #pragma unroll
            for (int e = 0; e < 8; e++)
                xs[nb][e * 512 + tid] = (_Float16)xv[e];
        }
        __syncthreads();
        buf = nb;
    }

    // ---- FC epilogue: logits = h @ Wfc + bfc (1280 outputs) ----
    for (int i = tid; i < 1280; i += 512) {
        const int row = i / 10, lab = i % 10;
        float acc = bfc[lab];
        #pragma unroll 8
        for (int k = 0; k < 128; k++)
            acc += (float)h_s[buf][row * HSTRIDE + k] * Wfc[k * 10 + lab];
        out[(size_t)(rbase + row) * 10 + lab] = acc;
    }
}

extern "C" void kernel_launch(void* const* d_in, const int* in_sizes, int n_in,
                              void* d_out, int out_size, void* d_ws, size_t ws_size,
                              hipStream_t stream) {
    const float* x   = (const float*)d_in[0];
    const float* W   = (const float*)d_in[1];
    const float* b   = (const float*)d_in[2];
    const float* Wfc = (const float*)d_in[3];
    const float* bfc = (const float*)d_in[4];
    float* out = (float*)d_out;

    const int B = in_sizes[0] / (28 * 28);   // 32768
    const int blocks = B / 128;              // 256 = one per CU
    lstm_r19<<<blocks, 512, 0, stream>>>(x, W, b, Wfc, bfc, out);
}